// Round 1
// baseline (249.672 us; speedup 1.0000x reference)
//
#include <hip/hip_runtime.h>
#include <math.h>

#define BB 1024
#define LL 256
#define VV 50000
#define EE 300
#define AA 30
#define WORD_THRES 0.2f
#define COS_EPS_F 1e-8f
#define NEG_INF_F -1e9f

// ---------------------------------------------------------------------------
// Kernel 1: cent[v] = max_a ( (cos(a_emb[a], w_emb[v]) > thres ? cos : 0) * w[a] )
// sim depends only on (aspect, vocab id) -> precompute a [V] table.
// ---------------------------------------------------------------------------
__global__ void __launch_bounds__(256) cent_kernel(
    const float* __restrict__ w_emb,     // [V, E]
    const float* __restrict__ a_emb,     // [A, E]
    const float* __restrict__ a_weight,  // [A]
    float* __restrict__ cent)            // [V]
{
    __shared__ float s_anorm[AA];
    __shared__ float s_aw[AA];
    const int t = threadIdx.x;

    if (t < AA) {
        float n2 = 0.f;
        const float* ar = a_emb + t * EE;
        for (int c = 0; c < EE; c += 4) {
            float4 x = *(const float4*)(ar + c);
            n2 += x.x * x.x + x.y * x.y + x.z * x.z + x.w * x.w;
        }
        s_anorm[t] = fmaxf(sqrtf(n2), COS_EPS_F);
        s_aw[t] = a_weight[t];
    }
    __syncthreads();

    const int v = blockIdx.x * blockDim.x + t;
    if (v >= VV) return;

    float acc[AA];
#pragma unroll
    for (int a = 0; a < AA; ++a) acc[a] = 0.f;
    float n2 = 0.f;

    const float* xr = w_emb + (size_t)v * EE;
    for (int c = 0; c < EE; c += 4) {
        float4 x = *(const float4*)(xr + c);
        n2 += x.x * x.x + x.y * x.y + x.z * x.z + x.w * x.w;
#pragma unroll
        for (int a = 0; a < AA; ++a) {
            // uniform address -> scalar loads, FMA with SGPR operand
            float4 av = *(const float4*)(a_emb + a * EE + c);
            acc[a] += av.x * x.x + av.y * x.y + av.z * x.z + av.w * x.w;
        }
    }

    const float xn = fmaxf(sqrtf(n2), COS_EPS_F);
    float m = 0.f;
#pragma unroll
    for (int a = 0; a < AA; ++a) {
        float cosv = acc[a] / (s_anorm[a] * xn);
        float val = (cosv > WORD_THRES) ? cosv * s_aw[a] : 0.f;
        m = fmaxf(m, val);  // val >= 0, so this is relu+max over aspects
    }
    cent[v] = m;
}

// ---------------------------------------------------------------------------
// Kernel 2: one block per batch row b (256 threads, thread t == position l).
//   gather cent -> reductions (len, centroid sum, softmax) -> attention out,
//   centroid_score out -> z[b,:] = sum_l a[l] * w_emb[id_l][:]  -> enc_out.
// ---------------------------------------------------------------------------
__device__ __forceinline__ float wave_sum(float x) {
#pragma unroll
    for (int o = 32; o > 0; o >>= 1) x += __shfl_down(x, o);
    return x;
}
__device__ __forceinline__ float wave_max(float x) {
#pragma unroll
    for (int o = 32; o > 0; o >>= 1) x = fmaxf(x, __shfl_down(x, o));
    return x;
}

__global__ void __launch_bounds__(256) row_kernel(
    const int* __restrict__ inputs,   // [B, L]
    const float* __restrict__ w_emb,  // [V, E]
    const float* __restrict__ cent,   // [V]
    float* __restrict__ out)          // enc_out [B,E] | a [B,L] | cs [B]
{
    const int b = blockIdx.x;
    const int t = threadIdx.x;          // == l
    const int wid = t >> 6, lane = t & 63;

    __shared__ float part[4];
    __shared__ float s_a[LL];
    __shared__ int s_id[LL];

    const int id = inputs[b * LL + t];
    const float c = cent[id];
    const float score = (c > 0.f) ? c : NEG_INF_F;
    const float cnt = (id != 0) ? 1.f : 0.f;

    // --- block reductions ---
    float s = wave_sum(c);
    if (lane == 0) part[wid] = s;
    __syncthreads();
    const float sum_c = part[0] + part[1] + part[2] + part[3];
    __syncthreads();

    s = wave_sum(cnt);
    if (lane == 0) part[wid] = s;
    __syncthreads();
    const float len = part[0] + part[1] + part[2] + part[3];
    __syncthreads();

    s = wave_max(score);
    if (lane == 0) part[wid] = s;
    __syncthreads();
    const float mx = fmaxf(fmaxf(part[0], part[1]), fmaxf(part[2], part[3]));
    __syncthreads();

    const float p = expf(score - mx);   // expf(-1e9)==0; all-masked row -> p=1
    s = wave_sum(p);
    if (lane == 0) part[wid] = s;
    __syncthreads();
    const float sum_p = part[0] + part[1] + part[2] + part[3];

    const float a_l = p / sum_p;
    const float cs = sum_c / (len + 1e-5f);
    const float gate = (cs > 1e-4f) ? 1.f : 0.f;

    // attention output
    out[BB * EE + b * LL + t] = a_l;
    if (t == 0) out[BB * EE + BB * LL + b] = cs;

    s_a[t] = a_l;
    s_id[t] = id;
    __syncthreads();

    // --- z phase: thread t handles column e=t (and e=256+t for t<44) ---
    float acc0 = 0.f, acc1 = 0.f;
    for (int l = 0; l < LL; ++l) {
        const float w = s_a[l];
        const float* row = w_emb + (size_t)s_id[l] * EE;
        acc0 += w * row[t];
        if (t < EE - LL) acc1 += w * row[LL + t];
    }
    out[b * EE + t] = acc0 * gate;
    if (t < EE - LL) out[b * EE + LL + t] = acc1 * gate;
}

// ---------------------------------------------------------------------------
extern "C" void kernel_launch(void* const* d_in, const int* in_sizes, int n_in,
                              void* d_out, int out_size, void* d_ws, size_t ws_size,
                              hipStream_t stream) {
    const int* inputs = (const int*)d_in[0];
    const float* w_emb = (const float*)d_in[1];
    const float* a_emb = (const float*)d_in[2];
    const float* a_weight = (const float*)d_in[3];
    float* out = (float*)d_out;
    float* cent = (float*)d_ws;  // 50000 floats = 200 KB scratch

    cent_kernel<<<(VV + 255) / 256, 256, 0, stream>>>(w_emb, a_emb, a_weight, cent);
    row_kernel<<<BB, 256, 0, stream>>>(inputs, w_emb, cent, out);
}

// Round 2
// 146.662 us; speedup vs baseline: 1.7024x; 1.7024x over previous
//
#include <hip/hip_runtime.h>
#include <math.h>

#define BB 1024
#define LL 256
#define VV 50000
#define EE 300
#define AA 30
#define WORD_THRES 0.2f
#define COS_EPS_F 1e-8f
#define NEG_INF_F -1e9f

// ---------------------------------------------------------------------------
// Kernel 1: cent[v] = max_a ( (cos(a_emb[a], w_emb[v]) > thres ? cos : 0) * w[a] )
// Layout: 4 lanes per vocab row, 2 rows per thread -> block of 256 handles 128 v.
// Grid 391 blocks (~1.5 blocks/CU, 6 waves/CU) vs round-1's 196 (-starved).
// ---------------------------------------------------------------------------
__global__ void __launch_bounds__(256) cent_kernel(
    const float* __restrict__ w_emb,     // [V, E]
    const float* __restrict__ a_emb,     // [A, E]
    const float* __restrict__ a_weight,  // [A]
    float* __restrict__ cent)            // [V]
{
    __shared__ float s_inv_anorm[AA];
    __shared__ float s_aw[AA];
    const int t = threadIdx.x;

    if (t < AA) {
        float n2 = 0.f;
        const float* ar = a_emb + t * EE;
        for (int c = 0; c < EE; c += 4) {
            float4 x = *(const float4*)(ar + c);
            n2 += x.x * x.x + x.y * x.y + x.z * x.z + x.w * x.w;
        }
        s_inv_anorm[t] = 1.f / fmaxf(sqrtf(n2), COS_EPS_F);
        s_aw[t] = a_weight[t];
    }
    __syncthreads();

    const int p = t & 3;        // lane within 4-lane group: float4-col p, p+4, ...
    const int slot = t >> 2;    // 64 slots per block
    const int v0 = blockIdx.x * 128 + slot;
    const int v1 = v0 + 64;
    const bool ok0 = v0 < VV, ok1 = v1 < VV;
    const float* r0 = w_emb + (size_t)(ok0 ? v0 : 0) * EE;
    const float* r1 = w_emb + (size_t)(ok1 ? v1 : 0) * EE;

    float acc0[AA], acc1[AA];
#pragma unroll
    for (int a = 0; a < AA; ++a) { acc0[a] = 0.f; acc1[a] = 0.f; }
    float n20 = 0.f, n21 = 0.f;

    // 75 float4 cols: k=0..17 cover j=4k+p (<=71), tail j=72+p for p<3
    for (int k = 0; k < 18; ++k) {
        const int j = 4 * k + p;
        const float4 w0 = *(const float4*)(r0 + 4 * j);
        const float4 w1 = *(const float4*)(r1 + 4 * j);
        n20 += w0.x * w0.x + w0.y * w0.y + w0.z * w0.z + w0.w * w0.w;
        n21 += w1.x * w1.x + w1.y * w1.y + w1.z * w1.z + w1.w * w1.w;
#pragma unroll
        for (int a = 0; a < AA; ++a) {
            const float4 av = *(const float4*)(a_emb + a * EE + 4 * j);
            acc0[a] += av.x * w0.x + av.y * w0.y + av.z * w0.z + av.w * w0.w;
            acc1[a] += av.x * w1.x + av.y * w1.y + av.z * w1.z + av.w * w1.w;
        }
    }
    if (p < 3) {
        const int j = 72 + p;
        const float4 w0 = *(const float4*)(r0 + 4 * j);
        const float4 w1 = *(const float4*)(r1 + 4 * j);
        n20 += w0.x * w0.x + w0.y * w0.y + w0.z * w0.z + w0.w * w0.w;
        n21 += w1.x * w1.x + w1.y * w1.y + w1.z * w1.z + w1.w * w1.w;
#pragma unroll
        for (int a = 0; a < AA; ++a) {
            const float4 av = *(const float4*)(a_emb + a * EE + 4 * j);
            acc0[a] += av.x * w0.x + av.y * w0.y + av.z * w0.z + av.w * w0.w;
            acc1[a] += av.x * w1.x + av.y * w1.y + av.z * w1.z + av.w * w1.w;
        }
    }

    // reduce partial dots across the 4-lane group (xor butterfly)
#pragma unroll
    for (int a = 0; a < AA; ++a) {
        acc0[a] += __shfl_xor(acc0[a], 1); acc0[a] += __shfl_xor(acc0[a], 2);
        acc1[a] += __shfl_xor(acc1[a], 1); acc1[a] += __shfl_xor(acc1[a], 2);
    }
    n20 += __shfl_xor(n20, 1); n20 += __shfl_xor(n20, 2);
    n21 += __shfl_xor(n21, 1); n21 += __shfl_xor(n21, 2);

    if (p == 0) {
        const float inv_x0 = 1.f / fmaxf(sqrtf(n20), COS_EPS_F);
        const float inv_x1 = 1.f / fmaxf(sqrtf(n21), COS_EPS_F);
        float m0 = 0.f, m1 = 0.f;
#pragma unroll
        for (int a = 0; a < AA; ++a) {
            const float c0 = acc0[a] * s_inv_anorm[a] * inv_x0;
            const float c1 = acc1[a] * s_inv_anorm[a] * inv_x1;
            m0 = fmaxf(m0, (c0 > WORD_THRES) ? c0 * s_aw[a] : 0.f);
            m1 = fmaxf(m1, (c1 > WORD_THRES) ? c1 * s_aw[a] : 0.f);
        }
        if (ok0) cent[v0] = m0;
        if (ok1) cent[v1] = m1;
    }
}

// ---------------------------------------------------------------------------
// Kernel 2: one block per batch row. Gather cent -> reductions -> attention.
// z-phase: a_l == 0 exactly for masked positions (expf(-1e9-mx)==0 when any
// active), so compact active (id, a_l) pairs and sum only those (~2-8 per row).
// ---------------------------------------------------------------------------
__device__ __forceinline__ float wave_sum(float x) {
#pragma unroll
    for (int o = 32; o > 0; o >>= 1) x += __shfl_down(x, o);
    return x;
}
__device__ __forceinline__ float wave_max(float x) {
#pragma unroll
    for (int o = 32; o > 0; o >>= 1) x = fmaxf(x, __shfl_down(x, o));
    return x;
}

__global__ void __launch_bounds__(256) row_kernel(
    const int* __restrict__ inputs,   // [B, L]
    const float* __restrict__ w_emb,  // [V, E]
    const float* __restrict__ cent,   // [V]
    float* __restrict__ out)          // enc_out [B,E] | a [B,L] | cs [B]
{
    const int b = blockIdx.x;
    const int t = threadIdx.x;          // == l
    const int wid = t >> 6, lane = t & 63;

    __shared__ float part[4];
    __shared__ int s_nact;
    __shared__ int s_act_id[LL];
    __shared__ float s_act_w[LL];

    const int id = inputs[b * LL + t];
    const float c = cent[id];
    const float score = (c > 0.f) ? c : NEG_INF_F;
    const float cnt = (id != 0) ? 1.f : 0.f;
    if (t == 0) s_nact = 0;

    // --- block reductions ---
    float s = wave_sum(c);
    if (lane == 0) part[wid] = s;
    __syncthreads();
    const float sum_c = part[0] + part[1] + part[2] + part[3];
    __syncthreads();

    s = wave_sum(cnt);
    if (lane == 0) part[wid] = s;
    __syncthreads();
    const float len = part[0] + part[1] + part[2] + part[3];
    __syncthreads();

    s = wave_max(score);
    if (lane == 0) part[wid] = s;
    __syncthreads();
    const float mx = fmaxf(fmaxf(part[0], part[1]), fmaxf(part[2], part[3]));
    __syncthreads();

    const float p = expf(score - mx);   // expf(-1e9)==0; all-masked row -> p=1
    s = wave_sum(p);
    if (lane == 0) part[wid] = s;
    __syncthreads();
    const float sum_p = part[0] + part[1] + part[2] + part[3];

    const float a_l = p / sum_p;
    const float cs = sum_c / (len + 1e-5f);
    const float gate = (cs > 1e-4f) ? 1.f : 0.f;

    out[BB * EE + b * LL + t] = a_l;            // attention
    if (t == 0) out[BB * EE + BB * LL + b] = cs;

    // compact active positions (score > -inf <=> cent > 0 <=> a_l can be > 0
    // whenever gate could be nonzero)
    if (score > -1e8f) {
        const int i = atomicAdd(&s_nact, 1);
        s_act_id[i] = id;
        s_act_w[i] = a_l;
    }
    __syncthreads();
    const int n = s_nact;

    // z over active entries only; thread t<75 owns float4 column t
    if (t < EE / 4) {
        float4 acc = {0.f, 0.f, 0.f, 0.f};
        for (int i = 0; i < n; ++i) {
            const float w = s_act_w[i];
            const float4 r = *(const float4*)(w_emb + (size_t)s_act_id[i] * EE + 4 * t);
            acc.x += w * r.x; acc.y += w * r.y; acc.z += w * r.z; acc.w += w * r.w;
        }
        acc.x *= gate; acc.y *= gate; acc.z *= gate; acc.w *= gate;
        *(float4*)(out + b * EE + 4 * t) = acc;
    }
}

// ---------------------------------------------------------------------------
extern "C" void kernel_launch(void* const* d_in, const int* in_sizes, int n_in,
                              void* d_out, int out_size, void* d_ws, size_t ws_size,
                              hipStream_t stream) {
    const int* inputs = (const int*)d_in[0];
    const float* w_emb = (const float*)d_in[1];
    const float* a_emb = (const float*)d_in[2];
    const float* a_weight = (const float*)d_in[3];
    float* out = (float*)d_out;
    float* cent = (float*)d_ws;  // 50000 floats = 200 KB scratch

    cent_kernel<<<(VV + 127) / 128, 256, 0, stream>>>(w_emb, a_emb, a_weight, cent);
    row_kernel<<<BB, 256, 0, stream>>>(inputs, w_emb, cent, out);
}

// Round 3
// 131.251 us; speedup vs baseline: 1.9023x; 1.1174x over previous
//
#include <hip/hip_runtime.h>
#include <math.h>

#define BB 1024
#define LL 256
#define VV 50000
#define EE 300
#define AA 30
#define WORD_THRES 0.2f
#define COS_EPS_F 1e-8f
#define NEG_INF_F -1e9f

// ---------------------------------------------------------------------------
// Kernel 1: cent[v] = max_a ( (cos(a_emb[a], w_emb[v]) > thres ? cos : 0) * w[a] )
// Block = 4 waves, 64 vocab rows (row <-> lane). Wave w owns E-chunk w
// (float4 cols 0-18 / 19-37 / 38-56 / 57-74). a_emb offsets are wave-uniform
// (readfirstlane) -> scalar loads. Cross-wave reduce via LDS (pad 31 = 2-way,
// free). Grid 782 blocks (~3 blocks/CU) vs round-2's 391.
// ---------------------------------------------------------------------------
__global__ void __launch_bounds__(256) cent_kernel(
    const float* __restrict__ w_emb,     // [V, E]
    const float* __restrict__ a_emb,     // [A, E]
    const float* __restrict__ a_weight,  // [A]
    float* __restrict__ cent)            // [V]
{
    __shared__ float s_scale[AA];        // 1 / max(||a||, eps)
    __shared__ float s_aw[AA];
    __shared__ float s_red[4 * 64 * 31]; // [wave][row][aspect(+pad)]
    __shared__ float s_n2[4 * 64];
    __shared__ float s_pm[64 * 5];

    const int t = threadIdx.x;
    const int lane = t & 63;
    const int w = t >> 6;

    // aspect norms: 8 lanes per aspect (groups never cross a wave boundary)
    {
        const int a = t >> 3, j = t & 7;
        if (a < AA) {
            const float* ar = a_emb + a * EE;
            float n2a = 0.f;
            for (int c = j; c < EE / 4; c += 8) {
                const float4 x = *(const float4*)(ar + 4 * c);
                n2a += x.x * x.x + x.y * x.y + x.z * x.z + x.w * x.w;
            }
            n2a += __shfl_xor(n2a, 1);
            n2a += __shfl_xor(n2a, 2);
            n2a += __shfl_xor(n2a, 4);
            if (j == 0) {
                s_scale[a] = 1.f / fmaxf(sqrtf(n2a), COS_EPS_F);
                s_aw[a] = a_weight[a];
            }
        }
    }

    const int v = blockIdx.x * 64 + lane;
    const bool okv = v < VV;
    const float* row = w_emb + (size_t)(okv ? v : 0) * EE;
    const int cb  = __builtin_amdgcn_readfirstlane((w == 3) ? 57 : w * 19);
    const int cnt = __builtin_amdgcn_readfirstlane((w == 3) ? 18 : 19);

    float acc[AA];
#pragma unroll
    for (int a = 0; a < AA; ++a) acc[a] = 0.f;
    float n2 = 0.f;

    for (int i = 0; i < cnt; ++i) {
        const float4 wv = *(const float4*)(row + 4 * (cb + i));
        n2 += wv.x * wv.x + wv.y * wv.y + wv.z * wv.z + wv.w * wv.w;
        const float* ac = a_emb + 4 * (cb + i);   // wave-uniform column base
#pragma unroll
        for (int a = 0; a < AA; ++a) {
            const float4 av = *(const float4*)(ac + a * EE);  // s_load
            acc[a] = fmaf(av.x, wv.x, fmaf(av.y, wv.y,
                     fmaf(av.z, wv.z, fmaf(av.w, wv.w, acc[a]))));
        }
    }

    // stage partials: addr stride 31 floats across lanes -> 2-way (free)
    float* my = s_red + (w * 64 + lane) * 31;
#pragma unroll
    for (int a = 0; a < AA; ++a) my[a] = acc[a];
    s_n2[w * 64 + lane] = n2;
    __syncthreads();

    // wave w reduces aspect group [8w, 8w+8) (group 3: 6 aspects) for all rows
    {
        const int a0 = w * 8;
        const int a1 = (w == 3) ? AA : a0 + 8;
        const float n2t = s_n2[lane] + s_n2[64 + lane] + s_n2[128 + lane] + s_n2[192 + lane];
        const float invx = 1.f / fmaxf(sqrtf(n2t), COS_EPS_F);
        float pm = 0.f;
        for (int a = a0; a < a1; ++a) {
            const float d = s_red[lane * 31 + a] + s_red[(64 + lane) * 31 + a] +
                            s_red[(128 + lane) * 31 + a] + s_red[(192 + lane) * 31 + a];
            const float cosv = d * s_scale[a] * invx;
            pm = fmaxf(pm, (cosv > WORD_THRES) ? cosv * s_aw[a] : 0.f);
        }
        s_pm[lane * 5 + w] = pm;
    }
    __syncthreads();

    if (t < 64 && okv) {
        cent[v] = fmaxf(fmaxf(s_pm[t * 5], s_pm[t * 5 + 1]),
                        fmaxf(s_pm[t * 5 + 2], s_pm[t * 5 + 3]));
    }
}

// ---------------------------------------------------------------------------
// Kernel 2: one block per batch row. 3 barriers total. Sparse z over the
// ~2-8 active positions (a_l == 0 exactly for masked positions).
// ---------------------------------------------------------------------------
__global__ void __launch_bounds__(256) row_kernel(
    const int* __restrict__ inputs,   // [B, L]
    const float* __restrict__ w_emb,  // [V, E]
    const float* __restrict__ cent,   // [V]
    float* __restrict__ out)          // enc_out [B,E] | a [B,L] | cs [B]
{
    const int b = blockIdx.x;
    const int t = threadIdx.x;          // == l
    const int wid = t >> 6, lane = t & 63;

    __shared__ float pA[4], pB[4], pC[4], pD[4];
    __shared__ int s_nact;
    __shared__ int s_act_id[LL];
    __shared__ float s_act_w[LL];

    const int id = inputs[b * LL + t];
    const float c = cent[id];
    const float score = (c > 0.f) ? c : NEG_INF_F;
    const float cnt = (id != 0) ? 1.f : 0.f;
    if (t == 0) s_nact = 0;

    // fused sum(c) / sum(cnt) / max(score) in one shuffle pass
    float s1 = c, s2 = cnt, s3 = score;
#pragma unroll
    for (int o = 32; o > 0; o >>= 1) {
        s1 += __shfl_down(s1, o);
        s2 += __shfl_down(s2, o);
        s3 = fmaxf(s3, __shfl_down(s3, o));
    }
    if (lane == 0) { pA[wid] = s1; pB[wid] = s2; pC[wid] = s3; }
    __syncthreads();

    const float sum_c = pA[0] + pA[1] + pA[2] + pA[3];
    const float len   = pB[0] + pB[1] + pB[2] + pB[3];
    const float mx    = fmaxf(fmaxf(pC[0], pC[1]), fmaxf(pC[2], pC[3]));

    const float p = expf(score - mx);   // expf(-1e9)==0; all-masked row -> p=1
    float s4 = p;
#pragma unroll
    for (int o = 32; o > 0; o >>= 1) s4 += __shfl_down(s4, o);
    if (lane == 0) pD[wid] = s4;
    __syncthreads();
    const float sum_p = pD[0] + pD[1] + pD[2] + pD[3];

    const float a_l = p / sum_p;
    const float cs = sum_c / (len + 1e-5f);
    const float gate = (cs > 1e-4f) ? 1.f : 0.f;

    out[BB * EE + b * LL + t] = a_l;            // attention
    if (t == 0) out[BB * EE + BB * LL + b] = cs;

    if (score > -1e8f) {                         // active <=> cent > 0
        const int i = atomicAdd(&s_nact, 1);
        s_act_id[i] = id;
        s_act_w[i] = a_l;
    }
    __syncthreads();
    const int n = s_nact;

    // z over active entries only; thread t<75 owns float4 column t
    if (t < EE / 4) {
        float4 acc = {0.f, 0.f, 0.f, 0.f};
        for (int i = 0; i < n; ++i) {
            const float wgt = s_act_w[i];
            const float4 r = *(const float4*)(w_emb + (size_t)s_act_id[i] * EE + 4 * t);
            acc.x += wgt * r.x; acc.y += wgt * r.y;
            acc.z += wgt * r.z; acc.w += wgt * r.w;
        }
        acc.x *= gate; acc.y *= gate; acc.z *= gate; acc.w *= gate;
        *(float4*)(out + b * EE + 4 * t) = acc;
    }
}

// ---------------------------------------------------------------------------
extern "C" void kernel_launch(void* const* d_in, const int* in_sizes, int n_in,
                              void* d_out, int out_size, void* d_ws, size_t ws_size,
                              hipStream_t stream) {
    const int* inputs = (const int*)d_in[0];
    const float* w_emb = (const float*)d_in[1];
    const float* a_emb = (const float*)d_in[2];
    const float* a_weight = (const float*)d_in[3];
    float* out = (float*)d_out;
    float* cent = (float*)d_ws;  // 50000 floats = 200 KB scratch

    cent_kernel<<<(VV + 63) / 64, 256, 0, stream>>>(w_emb, a_emb, a_weight, cent);
    row_kernel<<<BB, 256, 0, stream>>>(inputs, w_emb, cent, out);
}

// Round 4
// 125.243 us; speedup vs baseline: 1.9935x; 1.0480x over previous
//
#include <hip/hip_runtime.h>
#include <math.h>

#define BB 1024
#define LL 256
#define VV 50000
#define EE 300
#define AA 30
#define WORD_THRES 0.2f
#define COS_EPS_F 1e-8f
#define NEG_INF_F -1e9f

// ---------------------------------------------------------------------------
// Kernel 1: cent[v] = max_a ( (cos(a_emb[a], w_emb[v]) > thres ? cos : 0) * w[a] )
// Geometry: 4 lanes per vocab row (E-quarters), 2 rows per thread,
// 128 rows/block, grid 391. a_emb staged in LDS ([a][75] float4, 36 KB):
// inner-loop reads are 16-way broadcasts hitting disjoint bank groups
// across the 4 p-lanes -> conflict-free, no scalar-K$ thrash (round-3 bug).
// ---------------------------------------------------------------------------
__global__ void __launch_bounds__(256) cent_kernel(
    const float* __restrict__ w_emb,     // [V, E]
    const float* __restrict__ a_emb,     // [A, E]
    const float* __restrict__ a_weight,  // [A]
    float* __restrict__ cent)            // [V]
{
    __shared__ float4 s_a[AA * 75];      // a-major: s_a[a*75 + j], 36000 B
    __shared__ float s_scale[AA];        // 1 / max(||a||, eps)
    __shared__ float s_aw[AA];

    const int t = threadIdx.x;
    const float4* __restrict__ a4 = (const float4*)a_emb;   // [A][75]

    // stage a_emb -> LDS (straight copy, coalesced global, conflict-free LDS)
    for (int s = t; s < AA * 75; s += 256) s_a[s] = a4[s];

    // aspect norms: 8 lanes per aspect (fits in wave 0..3, groups don't cross waves)
    {
        const int a = t >> 3, j = t & 7;
        if (a < AA) {
            float n2a = 0.f;
            for (int c = j; c < 75; c += 8) {
                const float4 x = a4[a * 75 + c];
                n2a += x.x * x.x + x.y * x.y + x.z * x.z + x.w * x.w;
            }
            n2a += __shfl_xor(n2a, 1);
            n2a += __shfl_xor(n2a, 2);
            n2a += __shfl_xor(n2a, 4);
            if (j == 0) {
                s_scale[a] = 1.f / fmaxf(sqrtf(n2a), COS_EPS_F);
                s_aw[a] = a_weight[a];
            }
        }
    }
    __syncthreads();

    const int p = t & 3;        // E-quarter lane: handles float4-cols j = 4k+p
    const int slot = t >> 2;    // 64 row-slots per block
    const int v0 = blockIdx.x * 128 + slot;   // always < VV (last block base 49920)
    const int v1 = v0 + 64;
    const bool ok1 = v1 < VV;
    const float* __restrict__ r0 = w_emb + (size_t)v0 * EE;
    const float* __restrict__ r1 = w_emb + (size_t)(ok1 ? v1 : 0) * EE;

    float acc0[AA], acc1[AA];
#pragma unroll
    for (int a = 0; a < AA; ++a) { acc0[a] = 0.f; acc1[a] = 0.f; }
    float n20 = 0.f, n21 = 0.f;

    // 75 float4 cols: k=0..17 cover j=4k+p (<=71), tail j=72+p for p<3
    for (int k = 0; k < 18; ++k) {
        const int j = 4 * k + p;
        const float4 w0 = *(const float4*)(r0 + 4 * j);
        const float4 w1 = *(const float4*)(r1 + 4 * j);
        n20 += w0.x * w0.x + w0.y * w0.y + w0.z * w0.z + w0.w * w0.w;
        n21 += w1.x * w1.x + w1.y * w1.y + w1.z * w1.z + w1.w * w1.w;
        const float4* __restrict__ ap = s_a + j;
#pragma unroll
        for (int a = 0; a < AA; ++a) {
            const float4 av = ap[a * 75];        // LDS broadcast read
            acc0[a] = fmaf(av.x, w0.x, fmaf(av.y, w0.y,
                      fmaf(av.z, w0.z, fmaf(av.w, w0.w, acc0[a]))));
            acc1[a] = fmaf(av.x, w1.x, fmaf(av.y, w1.y,
                      fmaf(av.z, w1.z, fmaf(av.w, w1.w, acc1[a]))));
        }
    }
    if (p < 3) {
        const int j = 72 + p;
        const float4 w0 = *(const float4*)(r0 + 4 * j);
        const float4 w1 = *(const float4*)(r1 + 4 * j);
        n20 += w0.x * w0.x + w0.y * w0.y + w0.z * w0.z + w0.w * w0.w;
        n21 += w1.x * w1.x + w1.y * w1.y + w1.z * w1.z + w1.w * w1.w;
        const float4* __restrict__ ap = s_a + j;
#pragma unroll
        for (int a = 0; a < AA; ++a) {
            const float4 av = ap[a * 75];
            acc0[a] = fmaf(av.x, w0.x, fmaf(av.y, w0.y,
                      fmaf(av.z, w0.z, fmaf(av.w, w0.w, acc0[a]))));
            acc1[a] = fmaf(av.x, w1.x, fmaf(av.y, w1.y,
                      fmaf(av.z, w1.z, fmaf(av.w, w1.w, acc1[a]))));
        }
    }

    // reduce partial dots across the 4-lane group (xor butterfly)
#pragma unroll
    for (int a = 0; a < AA; ++a) {
        acc0[a] += __shfl_xor(acc0[a], 1); acc0[a] += __shfl_xor(acc0[a], 2);
        acc1[a] += __shfl_xor(acc1[a], 1); acc1[a] += __shfl_xor(acc1[a], 2);
    }
    n20 += __shfl_xor(n20, 1); n20 += __shfl_xor(n20, 2);
    n21 += __shfl_xor(n21, 1); n21 += __shfl_xor(n21, 2);

    if (p == 0) {
        const float inv_x0 = 1.f / fmaxf(sqrtf(n20), COS_EPS_F);
        const float inv_x1 = 1.f / fmaxf(sqrtf(n21), COS_EPS_F);
        float m0 = 0.f, m1 = 0.f;
#pragma unroll
        for (int a = 0; a < AA; ++a) {
            const float c0 = acc0[a] * s_scale[a] * inv_x0;
            const float c1 = acc1[a] * s_scale[a] * inv_x1;
            m0 = fmaxf(m0, (c0 > WORD_THRES) ? c0 * s_aw[a] : 0.f);
            m1 = fmaxf(m1, (c1 > WORD_THRES) ? c1 * s_aw[a] : 0.f);
        }
        cent[v0] = m0;
        if (ok1) cent[v1] = m1;
    }
}

// ---------------------------------------------------------------------------
// Kernel 2: one block per batch row. 3 barriers total. Sparse z over the
// ~2-8 active positions (a_l == 0 exactly for masked positions).
// ---------------------------------------------------------------------------
__global__ void __launch_bounds__(256) row_kernel(
    const int* __restrict__ inputs,   // [B, L]
    const float* __restrict__ w_emb,  // [V, E]
    const float* __restrict__ cent,   // [V]
    float* __restrict__ out)          // enc_out [B,E] | a [B,L] | cs [B]
{
    const int b = blockIdx.x;
    const int t = threadIdx.x;          // == l
    const int wid = t >> 6, lane = t & 63;

    __shared__ float pA[4], pB[4], pC[4], pD[4];
    __shared__ int s_nact;
    __shared__ int s_act_id[LL];
    __shared__ float s_act_w[LL];

    const int id = inputs[b * LL + t];
    const float c = cent[id];
    const float score = (c > 0.f) ? c : NEG_INF_F;
    const float cnt = (id != 0) ? 1.f : 0.f;
    if (t == 0) s_nact = 0;

    // fused sum(c) / sum(cnt) / max(score) in one shuffle pass
    float s1 = c, s2 = cnt, s3 = score;
#pragma unroll
    for (int o = 32; o > 0; o >>= 1) {
        s1 += __shfl_down(s1, o);
        s2 += __shfl_down(s2, o);
        s3 = fmaxf(s3, __shfl_down(s3, o));
    }
    if (lane == 0) { pA[wid] = s1; pB[wid] = s2; pC[wid] = s3; }
    __syncthreads();

    const float sum_c = pA[0] + pA[1] + pA[2] + pA[3];
    const float len   = pB[0] + pB[1] + pB[2] + pB[3];
    const float mx    = fmaxf(fmaxf(pC[0], pC[1]), fmaxf(pC[2], pC[3]));

    const float p = expf(score - mx);   // expf(-1e9)==0; all-masked row -> p=1
    float s4 = p;
#pragma unroll
    for (int o = 32; o > 0; o >>= 1) s4 += __shfl_down(s4, o);
    if (lane == 0) pD[wid] = s4;
    __syncthreads();
    const float sum_p = pD[0] + pD[1] + pD[2] + pD[3];

    const float a_l = p / sum_p;
    const float cs = sum_c / (len + 1e-5f);
    const float gate = (cs > 1e-4f) ? 1.f : 0.f;

    out[BB * EE + b * LL + t] = a_l;            // attention
    if (t == 0) out[BB * EE + BB * LL + b] = cs;

    if (score > -1e8f) {                         // active <=> cent > 0
        const int i = atomicAdd(&s_nact, 1);
        s_act_id[i] = id;
        s_act_w[i] = a_l;
    }
    __syncthreads();
    const int n = s_nact;

    // z over active entries only; thread t<75 owns float4 column t
    if (t < EE / 4) {
        float4 acc = {0.f, 0.f, 0.f, 0.f};
        for (int i = 0; i < n; ++i) {
            const float wgt = s_act_w[i];
            const float4 r = *(const float4*)(w_emb + (size_t)s_act_id[i] * EE + 4 * t);
            acc.x += wgt * r.x; acc.y += wgt * r.y;
            acc.z += wgt * r.z; acc.w += wgt * r.w;
        }
        acc.x *= gate; acc.y *= gate; acc.z *= gate; acc.w *= gate;
        *(float4*)(out + b * EE + 4 * t) = acc;
    }
}

// ---------------------------------------------------------------------------
extern "C" void kernel_launch(void* const* d_in, const int* in_sizes, int n_in,
                              void* d_out, int out_size, void* d_ws, size_t ws_size,
                              hipStream_t stream) {
    const int* inputs = (const int*)d_in[0];
    const float* w_emb = (const float*)d_in[1];
    const float* a_emb = (const float*)d_in[2];
    const float* a_weight = (const float*)d_in[3];
    float* out = (float*)d_out;
    float* cent = (float*)d_ws;  // 50000 floats = 200 KB scratch

    cent_kernel<<<(VV + 127) / 128, 256, 0, stream>>>(w_emb, a_emb, a_weight, cent);
    row_kernel<<<BB, 256, 0, stream>>>(inputs, w_emb, cent, out);
}